// Round 1
// baseline (1767.134 us; speedup 1.0000x reference)
//
#include <hip/hip_runtime.h>

typedef __bf16 bf16x8 __attribute__((ext_vector_type(8)));
typedef __bf16 bf16x4 __attribute__((ext_vector_type(4)));
typedef float  f32x4  __attribute__((ext_vector_type(4)));
typedef unsigned int  uint;
typedef unsigned short ushort_t;

static __device__ __forceinline__ ushort_t f2bf(float f) {
    uint u = __float_as_uint(f);
    return (ushort_t)((u + 0x7fffu + ((u >> 16) & 1u)) >> 16);
}

// ---------------- problem constants ----------------
// conv1: (32,1,120,640) * (256,1,30,160) stride (1,4) -> (32,256,91,121); use 90x120
// prim : (32,256,91,121)[90x120] * (256,256,10,10) stride 10 -> (32,256,9,12)
// caps : u(32,3456,8) -> u_predict(32,3456,5,16) -> routing -> (32,5,26) log_softmax

// ws layout (bytes)
constexpr size_t OFF_W1B = 0;
constexpr size_t SZ_W1B  = (size_t)256 * 4800 * 2;            //  2,457,600
constexpr size_t OFF_A2  = OFF_W1B + SZ_W1B;
constexpr size_t SZ_A2   = (size_t)256 * 25600 * 2;           // 13,107,200
constexpr size_t OFF_X   = OFF_A2 + SZ_A2;
constexpr size_t SZ_X    = (size_t)32 * 90 * 120 * 256 * 2;   // 176,947,200
constexpr size_t OFF_P   = OFF_X + SZ_X;
constexpr size_t SZ_P    = (size_t)4 * 256 * 32 * 112 * 4;    // 14,680,064
constexpr size_t OFF_UP  = OFF_X;                             // alias (used after X is consumed)
constexpr size_t WS_NEED = OFF_P + SZ_P;                      // ~207 MB

// ---------------- K0a: conv1_w -> bf16, same layout [oc][kh*160+kw] ----------------
__global__ void k0_w1(const float* __restrict__ w, ushort_t* __restrict__ o) {
    int i = blockIdx.x * 256 + threadIdx.x;   // grid 4800 * 256 == 1,228,800 exactly
    o[i] = f2bf(w[i]);
}

// ---------------- K0b: prim_w (oc2,ic,ph,pw) -> A2[oc2][p*256+ic] bf16 ----------------
__global__ void k0_a2(const float* __restrict__ w, ushort_t* __restrict__ o) {
    __shared__ ushort_t l[25600];
    int oc2 = blockIdx.x;                     // grid 256
    const float* src = w + (size_t)oc2 * 25600;
    for (int idx = threadIdx.x; idx < 25600; idx += 256) l[idx] = f2bf(src[idx]); // idx = ic*100+p
    __syncthreads();
    ushort_t* dst = o + (size_t)oc2 * 25600;
    for (int idx = threadIdx.x; idx < 25600; idx += 256) {    // idx = p*256+ic (coalesced write)
        int p = idx >> 8, ic = idx & 255;
        dst[idx] = l[ic * 100 + p];
    }
}

// ---------------- K1: conv1+bias+relu as im2col GEMM ----------------
// grid (2, 90, 32) = (oc half, h, b); 256 threads = 4 waves, wave tile 64x64, wg tile 128x128(120 valid)
// X out layout: [b][h][w][ic] bf16 (ic contiguous)
__global__ __launch_bounds__(256) void k1_conv1(const float* __restrict__ inp,
                                                const ushort_t* __restrict__ w1b,
                                                const float* __restrict__ cb,
                                                ushort_t* __restrict__ X) {
    __shared__ ushort_t smem[22152];          // A slab [128][168] (43008B) + brow[648]; epilogue aliases first 32KB
    ushort_t* As   = smem;                    // [128][168] padded rows (+8 elems) to break bank conflicts
    ushort_t* brow = smem + 128 * 168;        // [640]
    const int tid = threadIdx.x, lane = tid & 63, wid = tid >> 6;
    const int wm = (wid >> 1) * 64, wn = (wid & 1) * 64;
    const int mi = blockIdx.x, h = blockIdx.y, b = blockIdx.z;
    const int oc0 = mi * 128;
    const int l16 = lane & 15, g8 = (lane >> 4) * 8;
    f32x4 acc[4][4] = {};

#pragma unroll 1
    for (int kh = 0; kh < 30; ++kh) {
        __syncthreads();
        // stage A slab: 128 rows x 160 bf16 (2560 x 16B chunks)
        const ushort_t* wsrc = w1b + (size_t)oc0 * 4800 + kh * 160;
        for (int idx = tid; idx < 2560; idx += 256) {
            int r = idx / 20, c = idx % 20;
            *(uint4*)&As[r * 168 + c * 8] = *(const uint4*)&wsrc[(size_t)r * 4800 + c * 8];
        }
        // stage input row (b, h+kh) as bf16
        const float* irow = inp + ((size_t)b * 120 + h + kh) * 640;
        for (int j = tid; j < 160; j += 256) {
            float4 f = *(const float4*)&irow[j * 4];
            uint u0 = (uint)f2bf(f.x) | ((uint)f2bf(f.y) << 16);
            uint u1 = (uint)f2bf(f.z) | ((uint)f2bf(f.w) << 16);
            uint2 pk; pk.x = u0; pk.y = u1;
            *(uint2*)&brow[j * 4] = pk;
        }
        __syncthreads();
#pragma unroll
        for (int kwc = 0; kwc < 5; ++kwc) {
            bf16x8 af[4], bf[4];
#pragma unroll
            for (int mt = 0; mt < 4; ++mt)
                af[mt] = *(const bf16x8*)&As[(wm + mt * 16 + l16) * 168 + kwc * 32 + g8];
#pragma unroll
            for (int nt = 0; nt < 4; ++nt) {
                int n = wn + nt * 16 + l16;
                int w = n < 120 ? n : 119;                 // pad cols: clamp (masked on store)
                int e = 4 * w + kwc * 32 + g8;             // 8B aligned, not 16B -> two b64 reads
                union { bf16x8 v8; bf16x4 v4[2]; } fr;
                fr.v4[0] = *(const bf16x4*)&brow[e];
                fr.v4[1] = *(const bf16x4*)&brow[e + 4];
                bf[nt] = fr.v8;
            }
#pragma unroll
            for (int mt = 0; mt < 4; ++mt)
#pragma unroll
                for (int nt = 0; nt < 4; ++nt)
                    acc[mt][nt] = __builtin_amdgcn_mfma_f32_16x16x32_bf16(af[mt], bf[nt], acc[mt][nt], 0, 0, 0);
        }
    }
    // epilogue: bias + relu -> LDS transpose [w][oc] -> coalesced store ic-contiguous
    float cbv[4][4];
#pragma unroll
    for (int mt = 0; mt < 4; ++mt)
#pragma unroll
        for (int r = 0; r < 4; ++r)
            cbv[mt][r] = cb[oc0 + wm + mt * 16 + (lane >> 4) * 4 + r];
    __syncthreads();
    ushort_t* cs = smem;                      // [128 w][128 oc] bf16 (32KB, aliases As)
#pragma unroll
    for (int mt = 0; mt < 4; ++mt)
#pragma unroll
        for (int nt = 0; nt < 4; ++nt)
#pragma unroll
            for (int r = 0; r < 4; ++r) {
                int wl  = wn + nt * 16 + l16;                    // C col = lane&15
                int ocl = wm + mt * 16 + (lane >> 4) * 4 + r;    // C row = (lane>>4)*4 + reg
                float v = acc[mt][nt][r] + cbv[mt][r];
                v = v > 0.f ? v : 0.f;
                cs[wl * 128 + ocl] = f2bf(v);
            }
    __syncthreads();
    ushort_t* Xrow = X + ((size_t)b * 90 + h) * 120 * 256 + oc0;
    int c8 = (tid & 15) * 8;
    for (int w = tid >> 4; w < 120; w += 16)
        *(uint4*)&Xrow[(size_t)w * 256 + c8] = *(const uint4*)&cs[w * 128 + c8];
}

// ---------------- K2: prim conv GEMM, split-K over patch positions ----------------
// grid (2, 4, 32) = (oc2 half, split, b); 256 thr; wave owns 32 rows x 112 cols
// P[s][oc2][b][n(112)] fp32 partials
__global__ __launch_bounds__(256) void k2_prim(const ushort_t* __restrict__ X,
                                               const ushort_t* __restrict__ A2,
                                               float* __restrict__ P) {
    const int tid = threadIdx.x, lane = tid & 63, wid = tid >> 6;
    const int mi = blockIdx.x, s = blockIdx.y, b = blockIdx.z;
    const int msub = mi * 128 + wid * 32;
    const int l16 = lane & 15, g8 = (lane >> 4) * 8;
    f32x4 acc[2][7] = {};
    size_t aoff[2];
#pragma unroll
    for (int t = 0; t < 2; ++t) aoff[t] = (size_t)(msub + t * 16 + l16) * 25600 + g8;
    size_t noff[7];
#pragma unroll
    for (int nt = 0; nt < 7; ++nt) {
        int n = nt * 16 + l16; n = n < 108 ? n : 107;   // pad cols clamp
        int h2 = n / 12, w2 = n % 12;
        noff[nt] = (((size_t)b * 90 + 10 * h2) * 120 + 10 * w2) * 256 + g8;
    }
#pragma unroll 1
    for (int p = s * 25; p < s * 25 + 25; ++p) {
        int ph = p / 10, pw = p % 10;
        size_t xb = (size_t)(ph * 120 + pw) * 256;
        size_t ab = (size_t)p * 256;
#pragma unroll
        for (int icc = 0; icc < 8; ++icc) {
            bf16x8 af[2], bfr[7];
#pragma unroll
            for (int t = 0; t < 2; ++t)
                af[t] = *(const bf16x8*)&A2[aoff[t] + ab + icc * 32];
#pragma unroll
            for (int nt = 0; nt < 7; ++nt)
                bfr[nt] = *(const bf16x8*)&X[noff[nt] + xb + icc * 32];
#pragma unroll
            for (int t = 0; t < 2; ++t)
#pragma unroll
                for (int nt = 0; nt < 7; ++nt)
                    acc[t][nt] = __builtin_amdgcn_mfma_f32_16x16x32_bf16(af[t], bfr[nt], acc[t][nt], 0, 0, 0);
        }
    }
#pragma unroll
    for (int t = 0; t < 2; ++t)
#pragma unroll
        for (int nt = 0; nt < 7; ++nt)
#pragma unroll
            for (int r = 0; r < 4; ++r) {
                int n   = nt * 16 + l16;
                int oc2 = msub + t * 16 + (lane >> 4) * 4 + r;
                P[(((size_t)s * 256 + oc2) * 32 + b) * 112 + n] = acc[t][nt][r];
            }
}

// ---------------- K3: reduce partials + prim bias + squash + caps prediction ----------------
// thread per (b,i); UP[b][i][80] fp32
__global__ __launch_bounds__(256) void k3_caps(const float* __restrict__ P,
                                               const float* __restrict__ prim_b,
                                               const float* __restrict__ caps_w,
                                               float* __restrict__ UP) {
    int t = blockIdx.x * 256 + threadIdx.x;   // grid 432*256 == 110,592 exactly
    int b = t / 3456, i = t % 3456;
    int cap = i / 108, hw = i % 108;
    float ud[8], l2 = 0.f;
#pragma unroll
    for (int d = 0; d < 8; ++d) {
        int oc2 = cap * 8 + d;
        float v = prim_b[oc2];
#pragma unroll
        for (int s = 0; s < 4; ++s)
            v += P[(((size_t)s * 256 + oc2) * 32 + b) * 112 + hw];
        ud[d] = v; l2 += v * v;
    }
    float scale = sqrtf(l2) / (1.f + l2);     // squash factor
#pragma unroll
    for (int d = 0; d < 8; ++d) ud[d] *= scale;
    const float* cw = caps_w + (size_t)i * 640;
    float* up = UP + ((size_t)b * 3456 + i) * 80;
    for (int j = 0; j < 80; j += 4) {
        f32x4 o = {0.f, 0.f, 0.f, 0.f};
#pragma unroll
        for (int d = 0; d < 8; ++d) {
            f32x4 w = *(const f32x4*)&cw[d * 80 + j];
            o += ud[d] * w;
        }
        *(f32x4*)&up[j] = o;
    }
}

// ---------------- K4: routing (3 iters) + logits + log_softmax ----------------
// one wg per batch; b_batch rows thread-private in registers
__global__ __launch_bounds__(256) void k4_route(const float* __restrict__ UP,
                                                const float* __restrict__ b_route,
                                                const float* __restrict__ pred_w,
                                                const float* __restrict__ pred_b,
                                                const float* __restrict__ eos_w,
                                                const float* __restrict__ eos_b,
                                                float* __restrict__ out) {
    __shared__ float sred[4][80];
    __shared__ __attribute__((aligned(16))) float sv[80];
    __shared__ float sscale[5];
    __shared__ float lg[130];
    __shared__ float lse[5];
    const int tid = threadIdx.x, lane = tid & 63, wid = tid >> 6;
    const int b = blockIdx.x;

    float br[14][5];
#pragma unroll
    for (int q = 0; q < 14; ++q) {
        int i = tid + q * 256;
        if (i < 3456)
#pragma unroll
            for (int o = 0; o < 5; ++o) br[q][o] = b_route[i * 5 + o];
    }

#pragma unroll 1
    for (int it = 0; it <= 3; ++it) {         // it 0: initial c/s/v; 1..3: routing iters
        f32x4 a4[20];
#pragma unroll
        for (int q = 0; q < 20; ++q) a4[q] = f32x4{0.f, 0.f, 0.f, 0.f};
#pragma unroll 1
        for (int q = 0; q < 14; ++q) {
            int i = tid + q * 256;
            if (i < 3456) {
                const float* up = UP + ((size_t)b * 3456 + i) * 80;
                f32x4 u4[20];
#pragma unroll
                for (int r = 0; r < 20; ++r) u4[r] = *(const f32x4*)&up[r * 4];
                float bo[5];
#pragma unroll
                for (int o = 0; o < 5; ++o) {
                    float bv = br[q][o];
                    if (it > 0) {
                        f32x4 dv = u4[o * 4 + 0] * (*(const f32x4*)&sv[o * 16 + 0])
                                 + u4[o * 4 + 1] * (*(const f32x4*)&sv[o * 16 + 4])
                                 + u4[o * 4 + 2] * (*(const f32x4*)&sv[o * 16 + 8])
                                 + u4[o * 4 + 3] * (*(const f32x4*)&sv[o * 16 + 12]);
                        bv += dv[0] + dv[1] + dv[2] + dv[3];
                        br[q][o] = bv;
                    }
                    bo[o] = bv;
                }
                float m = fmaxf(fmaxf(fmaxf(bo[0], bo[1]), fmaxf(bo[2], bo[3])), bo[4]);
                float e[5], sum = 0.f;
#pragma unroll
                for (int o = 0; o < 5; ++o) { e[o] = __expf(bo[o] - m); sum += e[o]; }
                float inv = 1.f / sum;
#pragma unroll
                for (int o = 0; o < 5; ++o) {
                    float c = e[o] * inv;
#pragma unroll
                    for (int q2 = 0; q2 < 4; ++q2) a4[o * 4 + q2] += c * u4[o * 4 + q2];
                }
            }
        }
        // reduce s across wave, then across waves
#pragma unroll
        for (int off = 32; off >= 1; off >>= 1)
#pragma unroll
            for (int q = 0; q < 20; ++q)
#pragma unroll
                for (int c = 0; c < 4; ++c) a4[q][c] += __shfl_xor(a4[q][c], off, 64);
        if (lane == 0)
#pragma unroll
            for (int q = 0; q < 20; ++q)
#pragma unroll
                for (int c = 0; c < 4; ++c) sred[wid][q * 4 + c] = a4[q][c];
        __syncthreads();
        if (tid < 80) sv[tid] = sred[0][tid] + sred[1][tid] + sred[2][tid] + sred[3][tid];
        __syncthreads();
        if (tid < 5) {
            float l2 = 0.f;
            for (int d = 0; d < 16; ++d) { float x = sv[tid * 16 + d]; l2 += x * x; }
            sscale[tid] = sqrtf(l2) / (1.f + l2);
        }
        __syncthreads();
        if (tid < 80) sv[tid] *= sscale[tid / 16];
        __syncthreads();                       // sv now holds v for next iter
    }
    // logits + log_softmax
    if (tid < 130) {
        int o = tid / 26, j = tid % 26;
        const float* wv = (j < 25) ? &pred_w[j * 16] : &eos_w[0];
        float dot = (j < 25) ? pred_b[j] : eos_b[0];
        for (int d = 0; d < 16; ++d) dot += sv[o * 16 + d] * wv[d];
        lg[tid] = dot;
    }
    __syncthreads();
    if (tid < 5) {
        float m = lg[tid * 26];
        for (int j = 1; j < 26; ++j) m = fmaxf(m, lg[tid * 26 + j]);
        float sum = 0.f;
        for (int j = 0; j < 26; ++j) sum += expf(lg[tid * 26 + j] - m);
        lse[tid] = m + logf(sum);
    }
    __syncthreads();
    if (tid < 130) out[b * 130 + tid] = lg[tid] - lse[tid / 26];
}

// ---------------- launch ----------------
extern "C" void kernel_launch(void* const* d_in, const int* in_sizes, int n_in,
                              void* d_out, int out_size, void* d_ws, size_t ws_size,
                              hipStream_t stream) {
    const float* inp    = (const float*)d_in[0];
    const float* w1     = (const float*)d_in[1];
    const float* cb1    = (const float*)d_in[2];
    const float* w2     = (const float*)d_in[3];
    const float* pb2    = (const float*)d_in[4];
    const float* capsw  = (const float*)d_in[5];
    const float* broute = (const float*)d_in[6];
    const float* predw  = (const float*)d_in[7];
    const float* predb  = (const float*)d_in[8];
    const float* eosw   = (const float*)d_in[9];
    const float* eosb   = (const float*)d_in[10];
    float* out = (float*)d_out;
    char* ws = (char*)d_ws;
    if (ws_size < WS_NEED) return;            // if this trips, absmax will equal max|ref| (~4)

    ushort_t* w1b = (ushort_t*)(ws + OFF_W1B);
    ushort_t* a2  = (ushort_t*)(ws + OFF_A2);
    ushort_t* X   = (ushort_t*)(ws + OFF_X);
    float*    P   = (float*)(ws + OFF_P);
    float*    UP  = (float*)(ws + OFF_UP);

    k0_w1  <<<dim3(4800),      dim3(256), 0, stream>>>(w1, w1b);
    k0_a2  <<<dim3(256),       dim3(256), 0, stream>>>(w2, a2);
    k1_conv1<<<dim3(2, 90, 32), dim3(256), 0, stream>>>(inp, w1b, cb1, X);
    k2_prim <<<dim3(2, 4, 32),  dim3(256), 0, stream>>>(X, a2, P);
    k3_caps <<<dim3(432),      dim3(256), 0, stream>>>(P, pb2, capsw, UP);
    k4_route<<<dim3(32),       dim3(256), 0, stream>>>(UP, broute, predw, predb, eosw, eosb, out);
}

// Round 2
// 1755.498 us; speedup vs baseline: 1.0066x; 1.0066x over previous
//
#include <hip/hip_runtime.h>

typedef __bf16 bf16x8 __attribute__((ext_vector_type(8)));
typedef __bf16 bf16x4 __attribute__((ext_vector_type(4)));
typedef float  f32x4  __attribute__((ext_vector_type(4)));
typedef unsigned int  uint;
typedef unsigned short ushort_t;

static __device__ __forceinline__ ushort_t f2bf(float f) {
    uint u = __float_as_uint(f);
    return (ushort_t)((u + 0x7fffu + ((u >> 16) & 1u)) >> 16);
}

// ---------------- problem constants ----------------
// conv1: (32,1,120,640) * (256,1,30,160) stride (1,4) -> use 90x120 region
// prim : X(b,h,w,ic) * (256,256,10,10) stride 10 -> (32,256,9,12)
// caps : u(32,3456,8) -> u_predict(32,3456,5,16) -> routing -> (32,5,26) log_softmax

// ws layout (bytes)
constexpr size_t OFF_W1B = 0;
constexpr size_t SZ_W1B  = (size_t)256 * 4800 * 2;            //  2,457,600
constexpr size_t OFF_A2  = OFF_W1B + SZ_W1B;
constexpr size_t SZ_A2   = (size_t)256 * 25600 * 2;           // 13,107,200
constexpr size_t OFF_X   = OFF_A2 + SZ_A2;
constexpr size_t SZ_X    = (size_t)32 * 90 * 120 * 256 * 2;   // 176,947,200
constexpr size_t OFF_P   = OFF_X + SZ_X;
constexpr size_t SZ_P    = (size_t)4 * 256 * 32 * 112 * 4;    // 14,680,064
constexpr size_t OFF_UP  = OFF_X;                             // alias (used after X is consumed)
constexpr size_t WS_NEED = OFF_P + SZ_P;                      // ~207 MB

// ---------------- K0a: conv1_w -> bf16, same layout [oc][kh*160+kw] ----------------
__global__ void k0_w1(const float* __restrict__ w, ushort_t* __restrict__ o) {
    int i = blockIdx.x * 256 + threadIdx.x;   // grid 4800 * 256 == 1,228,800 exactly
    o[i] = f2bf(w[i]);
}

// ---------------- K0b: prim_w (oc2,ic,ph,pw) -> A2[oc2][p*256+ic] bf16 ----------------
__global__ void k0_a2(const float* __restrict__ w, ushort_t* __restrict__ o) {
    __shared__ ushort_t l[25600];
    int oc2 = blockIdx.x;                     // grid 256
    const float* src = w + (size_t)oc2 * 25600;
    for (int idx = threadIdx.x; idx < 25600; idx += 256) l[idx] = f2bf(src[idx]); // idx = ic*100+p
    __syncthreads();
    ushort_t* dst = o + (size_t)oc2 * 25600;
    for (int idx = threadIdx.x; idx < 25600; idx += 256) {    // idx = p*256+ic (coalesced write)
        int p = idx >> 8, ic = idx & 255;
        dst[idx] = l[ic * 100 + p];
    }
}

// ---------------- K1: conv1+bias+relu as im2col GEMM (v2) ----------------
// grid (45, 32) = (h-pair, b); 512 threads = 8 waves = 4 M-groups x 2 h-rows.
// Block tile: M=256 oc x N=240 (two h rows of 120, exact). Wave tile 64 x 128 (120 valid).
// B-fragment dedupe: frag addr = 4*l16+g8 + 32*(2*nt+kwc) -> only t=0..18 distinct frags/kh,
// cached in registers. brow rows padded to 704 els (zeros) so pad columns stay linear.
// LDS: As[256][168] (86016B) + brow[2][704] (2816B); epilogue aliases as cs[240][264] (126720B).
__global__ __launch_bounds__(512, 2) void k1_conv1(const float* __restrict__ inp,
                                                   const ushort_t* __restrict__ w1b,
                                                   const float* __restrict__ cb,
                                                   ushort_t* __restrict__ X) {
    __shared__ ushort_t smem[63360];          // 126720 B
    ushort_t* As   = smem;                    // [256][168] (+8 pad: stride 336B -> uniform 2-way banks)
    ushort_t* brow = smem + 256 * 168;        // [2][704]
    const int tid = threadIdx.x, lane = tid & 63, wid = tid >> 6;
    const int wm = (wid & 3) * 64;            // M-group: 0/64/128/192
    const int hr = wid >> 2;                  // h-row within pair: 0/1
    const int hp = blockIdx.x, b = blockIdx.y;
    const int h0 = hp * 2;
    const int l16 = lane & 15, g8 = (lane >> 4) * 8;
    const int bbase = hr * 704 + 4 * l16 + g8;
    f32x4 acc[4][8] = {};

#pragma unroll 1
    for (int kh = 0; kh < 30; ++kh) {
        __syncthreads();
        // stage A: 256 rows x 160 els (5120 x 16B chunks, 10 per thread)
        const ushort_t* wsrc = w1b + kh * 160;
        for (int idx = tid; idx < 5120; idx += 512) {
            int r = idx / 20, c = idx % 20;
            *(uint4*)&As[r * 168 + c * 8] = *(const uint4*)&wsrc[(size_t)r * 4800 + c * 8];
        }
        // stage brow: 2 input rows -> bf16, els 640..703 zeroed
        if (tid < 352) {
            int r = tid / 176, c = tid % 176;
            uint2 pk;
            if (c < 160) {
                const float* irow = inp + ((size_t)b * 120 + h0 + kh + r) * 640;
                float4 f = *(const float4*)&irow[c * 4];
                pk.x = (uint)f2bf(f.x) | ((uint)f2bf(f.y) << 16);
                pk.y = (uint)f2bf(f.z) | ((uint)f2bf(f.w) << 16);
            } else { pk.x = 0u; pk.y = 0u; }
            *(uint2*)&brow[r * 704 + c * 4] = pk;
        }
        __syncthreads();
        // B-fragment cache: 19 frags, t = 2*nt + kwc
        bf16x8 bc[19];
#pragma unroll
        for (int t = 0; t < 19; ++t) {
            union { bf16x8 v8; bf16x4 v4[2]; } fr;
            fr.v4[0] = *(const bf16x4*)&brow[bbase + 32 * t];
            fr.v4[1] = *(const bf16x4*)&brow[bbase + 32 * t + 4];
            bc[t] = fr.v8;
        }
#pragma unroll
        for (int kwc = 0; kwc < 5; ++kwc) {
            bf16x8 af[4];
#pragma unroll
            for (int mt = 0; mt < 4; ++mt)
                af[mt] = *(const bf16x8*)&As[(wm + mt * 16 + l16) * 168 + kwc * 32 + g8];
#pragma unroll
            for (int nt = 0; nt < 8; ++nt)
#pragma unroll
                for (int mt = 0; mt < 4; ++mt)
                    acc[mt][nt] = __builtin_amdgcn_mfma_f32_16x16x32_bf16(af[mt], bc[2 * nt + kwc], acc[mt][nt], 0, 0, 0);
        }
    }
    // epilogue: bias+relu -> LDS transpose cs[240 w][264 (256 oc + pad)] -> coalesced store
    float cbv[4][4];
#pragma unroll
    for (int mt = 0; mt < 4; ++mt)
#pragma unroll
        for (int r = 0; r < 4; ++r)
            cbv[mt][r] = cb[wm + mt * 16 + (lane >> 4) * 4 + r];
    __syncthreads();
    ushort_t* cs = smem;                      // [240][264] (stride 528B = 132 words == 4 mod 32 -> 2-way)
    const int hbase = hr * 120;
#pragma unroll
    for (int nt = 0; nt < 8; ++nt) {
        int wg = nt * 16 + l16;
        if (wg < 120) {
#pragma unroll
            for (int mt = 0; mt < 4; ++mt)
#pragma unroll
                for (int r = 0; r < 4; ++r) {
                    int oc = wm + mt * 16 + (lane >> 4) * 4 + r;
                    float v = acc[mt][nt][r] + cbv[mt][r];
                    v = v > 0.f ? v : 0.f;
                    cs[(hbase + wg) * 264 + oc] = f2bf(v);
                }
        }
    }
    __syncthreads();
    // rows h0,h0+1 are contiguous in X: offset = w*256 for w in 0..239
    ushort_t* Xbase = X + ((size_t)b * 90 + h0) * 120 * 256;
    for (int idx = tid; idx < 7680; idx += 512) {            // 240*256/8 chunks
        int w = idx >> 5, c = (idx & 31) * 8;
        *(uint4*)&Xbase[(size_t)w * 256 + c] = *(const uint4*)&cs[w * 264 + c];
    }
}

// ---------------- K2: prim conv GEMM, split-K over patch positions ----------------
// grid (2, 4, 32) = (oc2 half, split, b); 256 thr; wave owns 32 rows x 112 cols
// P[s][oc2][b][n(112)] fp32 partials
__global__ __launch_bounds__(256) void k2_prim(const ushort_t* __restrict__ X,
                                               const ushort_t* __restrict__ A2,
                                               float* __restrict__ P) {
    const int tid = threadIdx.x, lane = tid & 63, wid = tid >> 6;
    const int mi = blockIdx.x, s = blockIdx.y, b = blockIdx.z;
    const int msub = mi * 128 + wid * 32;
    const int l16 = lane & 15, g8 = (lane >> 4) * 8;
    f32x4 acc[2][7] = {};
    size_t aoff[2];
#pragma unroll
    for (int t = 0; t < 2; ++t) aoff[t] = (size_t)(msub + t * 16 + l16) * 25600 + g8;
    size_t noff[7];
#pragma unroll
    for (int nt = 0; nt < 7; ++nt) {
        int n = nt * 16 + l16; n = n < 108 ? n : 107;   // pad cols clamp
        int h2 = n / 12, w2 = n % 12;
        noff[nt] = (((size_t)b * 90 + 10 * h2) * 120 + 10 * w2) * 256 + g8;
    }
#pragma unroll 1
    for (int p = s * 25; p < s * 25 + 25; ++p) {
        int ph = p / 10, pw = p % 10;
        size_t xb = (size_t)(ph * 120 + pw) * 256;
        size_t ab = (size_t)p * 256;
#pragma unroll
        for (int icc = 0; icc < 8; ++icc) {
            bf16x8 af[2], bfr[7];
#pragma unroll
            for (int t = 0; t < 2; ++t)
                af[t] = *(const bf16x8*)&A2[aoff[t] + ab + icc * 32];
#pragma unroll
            for (int nt = 0; nt < 7; ++nt)
                bfr[nt] = *(const bf16x8*)&X[noff[nt] + xb + icc * 32];
#pragma unroll
            for (int t = 0; t < 2; ++t)
#pragma unroll
                for (int nt = 0; nt < 7; ++nt)
                    acc[t][nt] = __builtin_amdgcn_mfma_f32_16x16x32_bf16(af[t], bfr[nt], acc[t][nt], 0, 0, 0);
        }
    }
#pragma unroll
    for (int t = 0; t < 2; ++t)
#pragma unroll
        for (int nt = 0; nt < 7; ++nt)
#pragma unroll
            for (int r = 0; r < 4; ++r) {
                int n   = nt * 16 + l16;
                int oc2 = msub + t * 16 + (lane >> 4) * 4 + r;
                P[(((size_t)s * 256 + oc2) * 32 + b) * 112 + n] = acc[t][nt][r];
            }
}

// ---------------- K3: reduce partials + prim bias + squash + caps prediction ----------------
// thread per (b,i); UP[b][i][80] fp32
__global__ __launch_bounds__(256) void k3_caps(const float* __restrict__ P,
                                               const float* __restrict__ prim_b,
                                               const float* __restrict__ caps_w,
                                               float* __restrict__ UP) {
    int t = blockIdx.x * 256 + threadIdx.x;   // grid 432*256 == 110,592 exactly
    int b = t / 3456, i = t % 3456;
    int cap = i / 108, hw = i % 108;
    float ud[8], l2 = 0.f;
#pragma unroll
    for (int d = 0; d < 8; ++d) {
        int oc2 = cap * 8 + d;
        float v = prim_b[oc2];
#pragma unroll
        for (int s = 0; s < 4; ++s)
            v += P[(((size_t)s * 256 + oc2) * 32 + b) * 112 + hw];
        ud[d] = v; l2 += v * v;
    }
    float scale = sqrtf(l2) / (1.f + l2);     // squash factor
#pragma unroll
    for (int d = 0; d < 8; ++d) ud[d] *= scale;
    const float* cw = caps_w + (size_t)i * 640;
    float* up = UP + ((size_t)b * 3456 + i) * 80;
    for (int j = 0; j < 80; j += 4) {
        f32x4 o = {0.f, 0.f, 0.f, 0.f};
#pragma unroll
        for (int d = 0; d < 8; ++d) {
            f32x4 w = *(const f32x4*)&cw[d * 80 + j];
            o += ud[d] * w;
        }
        *(f32x4*)&up[j] = o;
    }
}

// ---------------- K4: routing (3 iters) + logits + log_softmax ----------------
// one wg per batch; b_batch thread-private in registers
__global__ __launch_bounds__(256) void k4_route(const float* __restrict__ UP,
                                                const float* __restrict__ b_route,
                                                const float* __restrict__ pred_w,
                                                const float* __restrict__ pred_b,
                                                const float* __restrict__ eos_w,
                                                const float* __restrict__ eos_b,
                                                float* __restrict__ out) {
    __shared__ float sred[4][80];
    __shared__ __attribute__((aligned(16))) float sv[80];
    __shared__ float sscale[5];
    __shared__ float lg[130];
    __shared__ float lse[5];
    const int tid = threadIdx.x, lane = tid & 63, wid = tid >> 6;
    const int b = blockIdx.x;

    float br[14][5];
#pragma unroll
    for (int q = 0; q < 14; ++q) {
        int i = tid + q * 256;
        if (i < 3456)
#pragma unroll
            for (int o = 0; o < 5; ++o) br[q][o] = b_route[i * 5 + o];
    }

#pragma unroll 1
    for (int it = 0; it <= 3; ++it) {         // it 0: initial c/s/v; 1..3: routing iters
        f32x4 a4[20];
#pragma unroll
        for (int q = 0; q < 20; ++q) a4[q] = f32x4{0.f, 0.f, 0.f, 0.f};
#pragma unroll 1
        for (int q = 0; q < 14; ++q) {
            int i = tid + q * 256;
            if (i < 3456) {
                const float* up = UP + ((size_t)b * 3456 + i) * 80;
                f32x4 u4[20];
#pragma unroll
                for (int r = 0; r < 20; ++r) u4[r] = *(const f32x4*)&up[r * 4];
                float bo[5];
#pragma unroll
                for (int o = 0; o < 5; ++o) {
                    float bv = br[q][o];
                    if (it > 0) {
                        f32x4 dv = u4[o * 4 + 0] * (*(const f32x4*)&sv[o * 16 + 0])
                                 + u4[o * 4 + 1] * (*(const f32x4*)&sv[o * 16 + 4])
                                 + u4[o * 4 + 2] * (*(const f32x4*)&sv[o * 16 + 8])
                                 + u4[o * 4 + 3] * (*(const f32x4*)&sv[o * 16 + 12]);
                        bv += dv[0] + dv[1] + dv[2] + dv[3];
                        br[q][o] = bv;
                    }
                    bo[o] = bv;
                }
                float m = fmaxf(fmaxf(fmaxf(bo[0], bo[1]), fmaxf(bo[2], bo[3])), bo[4]);
                float e[5], sum = 0.f;
#pragma unroll
                for (int o = 0; o < 5; ++o) { e[o] = __expf(bo[o] - m); sum += e[o]; }
                float inv = 1.f / sum;
#pragma unroll
                for (int o = 0; o < 5; ++o) {
                    float c = e[o] * inv;
#pragma unroll
                    for (int q2 = 0; q2 < 4; ++q2) a4[o * 4 + q2] += c * u4[o * 4 + q2];
                }
            }
        }
        // reduce s across wave, then across waves
#pragma unroll
        for (int off = 32; off >= 1; off >>= 1)
#pragma unroll
            for (int q = 0; q < 20; ++q)
#pragma unroll
                for (int c = 0; c < 4; ++c) a4[q][c] += __shfl_xor(a4[q][c], off, 64);
        if (lane == 0)
#pragma unroll
            for (int q = 0; q < 20; ++q)
#pragma unroll
                for (int c = 0; c < 4; ++c) sred[wid][q * 4 + c] = a4[q][c];
        __syncthreads();
        if (tid < 80) sv[tid] = sred[0][tid] + sred[1][tid] + sred[2][tid] + sred[3][tid];
        __syncthreads();
        if (tid < 5) {
            float l2 = 0.f;
            for (int d = 0; d < 16; ++d) { float x = sv[tid * 16 + d]; l2 += x * x; }
            sscale[tid] = sqrtf(l2) / (1.f + l2);
        }
        __syncthreads();
        if (tid < 80) sv[tid] *= sscale[tid / 16];
        __syncthreads();                       // sv now holds v for next iter
    }
    // logits + log_softmax
    if (tid < 130) {
        int o = tid / 26, j = tid % 26;
        const float* wv = (j < 25) ? &pred_w[j * 16] : &eos_w[0];
        float dot = (j < 25) ? pred_b[j] : eos_b[0];
        for (int d = 0; d < 16; ++d) dot += sv[o * 16 + d] * wv[d];
        lg[tid] = dot;
    }
    __syncthreads();
    if (tid < 5) {
        float m = lg[tid * 26];
        for (int j = 1; j < 26; ++j) m = fmaxf(m, lg[tid * 26 + j]);
        float sum = 0.f;
        for (int j = 0; j < 26; ++j) sum += expf(lg[tid * 26 + j] - m);
        lse[tid] = m + logf(sum);
    }
    __syncthreads();
    if (tid < 130) out[b * 130 + tid] = lg[tid] - lse[tid / 26];
}

// ---------------- launch ----------------
extern "C" void kernel_launch(void* const* d_in, const int* in_sizes, int n_in,
                              void* d_out, int out_size, void* d_ws, size_t ws_size,
                              hipStream_t stream) {
    const float* inp    = (const float*)d_in[0];
    const float* w1     = (const float*)d_in[1];
    const float* cb1    = (const float*)d_in[2];
    const float* w2     = (const float*)d_in[3];
    const float* pb2    = (const float*)d_in[4];
    const float* capsw  = (const float*)d_in[5];
    const float* broute = (const float*)d_in[6];
    const float* predw  = (const float*)d_in[7];
    const float* predb  = (const float*)d_in[8];
    const float* eosw   = (const float*)d_in[9];
    const float* eosb   = (const float*)d_in[10];
    float* out = (float*)d_out;
    char* ws = (char*)d_ws;
    if (ws_size < WS_NEED) return;

    ushort_t* w1b = (ushort_t*)(ws + OFF_W1B);
    ushort_t* a2  = (ushort_t*)(ws + OFF_A2);
    ushort_t* X   = (ushort_t*)(ws + OFF_X);
    float*    P   = (float*)(ws + OFF_P);
    float*    UP  = (float*)(ws + OFF_UP);

    k0_w1   <<<dim3(4800),     dim3(256), 0, stream>>>(w1, w1b);
    k0_a2   <<<dim3(256),      dim3(256), 0, stream>>>(w2, a2);
    k1_conv1<<<dim3(45, 32),   dim3(512), 0, stream>>>(inp, w1b, cb1, X);
    k2_prim <<<dim3(2, 4, 32), dim3(256), 0, stream>>>(X, a2, P);
    k3_caps <<<dim3(432),      dim3(256), 0, stream>>>(P, pb2, capsw, UP);
    k4_route<<<dim3(32),       dim3(256), 0, stream>>>(UP, broute, predw, predb, eosw, eosb, out);
}

// Round 3
// 1228.475 us; speedup vs baseline: 1.4385x; 1.4290x over previous
//
#include <hip/hip_runtime.h>

typedef __bf16 bf16x8 __attribute__((ext_vector_type(8)));
typedef __bf16 bf16x4 __attribute__((ext_vector_type(4)));
typedef float  f32x4  __attribute__((ext_vector_type(4)));
typedef unsigned int  uint;
typedef unsigned short ushort_t;

static __device__ __forceinline__ ushort_t f2bf(float f) {
    uint u = __float_as_uint(f);
    return (ushort_t)((u + 0x7fffu + ((u >> 16) & 1u)) >> 16);
}

// ---------------- problem constants ----------------
// conv1: (32,1,120,640) * (256,1,30,160) stride (1,4) -> use 90x120 region
// prim : X(b,h,w,ic) * (256,256,10,10) stride 10 -> (32,256,9,12)
// caps : u(32,3456,8) -> u_predict(32,3456,5,16) -> routing -> (32,5,26) log_softmax

// ws layout (bytes)
constexpr size_t OFF_W1F = 0;
constexpr size_t SZ_W1F  = (size_t)256 * 4800 * 2;            //  2,457,600 (frag-major)
constexpr size_t OFF_A2  = OFF_W1F + SZ_W1F;
constexpr size_t SZ_A2   = (size_t)256 * 25600 * 2;           // 13,107,200
constexpr size_t OFF_X   = OFF_A2 + SZ_A2;
constexpr size_t SZ_X    = (size_t)32 * 90 * 120 * 256 * 2;   // 176,947,200
constexpr size_t OFF_P   = OFF_X + SZ_X;
constexpr size_t SZ_P    = (size_t)4 * 256 * 32 * 112 * 4;    // 14,680,064
constexpr size_t OFF_UP  = OFF_X;                             // alias (used after X is consumed)
constexpr size_t WS_NEED = OFF_P + SZ_P;                      // ~207 MB

// ---------------- K0a: conv1_w -> bf16 MFMA-fragment-major layout ----------------
// w1f flat index = ((kh*16 + ocb)*5 + kwc)*512 + lane*8 + j
//   element = w1[(ocb*16 + (lane&15)) * 4800 + kh*160 + kwc*32 + (lane>>4)*8 + j]
// One K1 A-fragment load = global_load_dwordx4 at (q*512 + lane*8), fully coalesced.
__global__ void k0_w1(const float* __restrict__ w, ushort_t* __restrict__ o) {
    int t = blockIdx.x * 256 + threadIdx.x;   // grid 600*256 == 153,600 exactly
    int l   = t & 63;
    int q   = t >> 6;                          // 0..2399
    int kwc = q % 5;
    int ocb = (q / 5) % 16;
    int kh  = q / 80;
    const float* src = w + (size_t)(ocb * 16 + (l & 15)) * 4800 + kh * 160 + kwc * 32 + (l >> 4) * 8;
    float4 f0 = *(const float4*)src;
    float4 f1 = *(const float4*)(src + 4);
    uint4 pk;
    pk.x = (uint)f2bf(f0.x) | ((uint)f2bf(f0.y) << 16);
    pk.y = (uint)f2bf(f0.z) | ((uint)f2bf(f0.w) << 16);
    pk.z = (uint)f2bf(f1.x) | ((uint)f2bf(f1.y) << 16);
    pk.w = (uint)f2bf(f1.z) | ((uint)f2bf(f1.w) << 16);
    *(uint4*)&o[(size_t)t * 8] = pk;
}

// ---------------- K0b: prim_w (oc2,ic,ph,pw) -> A2[oc2][p*256+ic] bf16 ----------------
__global__ void k0_a2(const float* __restrict__ w, ushort_t* __restrict__ o) {
    __shared__ ushort_t l[25600];
    int oc2 = blockIdx.x;                     // grid 256
    const float* src = w + (size_t)oc2 * 25600;
    for (int idx = threadIdx.x; idx < 25600; idx += 256) l[idx] = f2bf(src[idx]); // idx = ic*100+p
    __syncthreads();
    ushort_t* dst = o + (size_t)oc2 * 25600;
    for (int idx = threadIdx.x; idx < 25600; idx += 256) {    // idx = p*256+ic (coalesced write)
        int p = idx >> 8, ic = idx & 255;
        dst[idx] = l[ic * 100 + p];
    }
}

// ---------------- K1: conv1+bias+relu as im2col GEMM (v3: A direct from L2) ----------------
// grid (90, 32) = (h, b); 256 threads = 4 waves, wave tile 64 oc x 128 w (120 valid).
// A fragments: coalesced global_load_dwordx4 from w1f (L2-resident, no LDS round trip).
// B: all 30 input rows staged to LDS ONCE (zero-padded to 704 els) -> K-loop has NO barriers.
// B-fragment dedupe: frag addr = 4*l16+g8 + 32*(2*nt+kwc); 19 distinct frags/kh in registers.
// LDS: brow[30][704] = 42.2 KB; epilogue aliases cs[120][264] = 63.4 KB -> 2 blocks/CU.
__global__ __launch_bounds__(256, 2) void k1_conv1(const float* __restrict__ inp,
                                                   const ushort_t* __restrict__ w1f,
                                                   const float* __restrict__ cb,
                                                   ushort_t* __restrict__ X) {
    __shared__ ushort_t smem[31680];          // 63,360 B
    ushort_t* brow = smem;                    // [30][704]
    const int tid = threadIdx.x, lane = tid & 63, wid = tid >> 6;
    const int wm = wid * 64;                  // M-group: 0/64/128/192
    const int h = blockIdx.x, b = blockIdx.y;
    const int l16 = lane & 15, g8 = (lane >> 4) * 8;
    const int bbase = 4 * l16 + g8;
    f32x4 acc[4][8] = {};

    // stage 30 input rows (h..h+29) as bf16, cols 640..703 zeroed
    for (int idx = tid; idx < 5280; idx += 256) {
        int r = idx / 176, c = idx % 176;
        uint2 pk; pk.x = 0u; pk.y = 0u;
        if (c < 160) {
            const float* irow = inp + ((size_t)b * 120 + h + r) * 640;
            float4 f = *(const float4*)&irow[c * 4];
            pk.x = (uint)f2bf(f.x) | ((uint)f2bf(f.y) << 16);
            pk.y = (uint)f2bf(f.z) | ((uint)f2bf(f.w) << 16);
        }
        *(uint2*)&brow[r * 704 + c * 4] = pk;
    }
    __syncthreads();

#pragma unroll 1
    for (int kh = 0; kh < 30; ++kh) {
        // B-fragment cache: 19 frags, t = 2*nt + kwc
        bf16x8 bc[19];
        const int rb = kh * 704 + bbase;
#pragma unroll
        for (int t = 0; t < 19; ++t) {
            union { bf16x8 v8; bf16x4 v4[2]; } fr;
            fr.v4[0] = *(const bf16x4*)&brow[rb + 32 * t];
            fr.v4[1] = *(const bf16x4*)&brow[rb + 32 * t + 4];
            bc[t] = fr.v8;
        }
#pragma unroll
        for (int kwc = 0; kwc < 5; ++kwc) {
            bf16x8 af[4];
#pragma unroll
            for (int mt = 0; mt < 4; ++mt) {
                int q = (kh * 16 + wid * 4 + mt) * 5 + kwc;
                af[mt] = *(const bf16x8*)&w1f[(size_t)q * 512 + lane * 8];
            }
#pragma unroll
            for (int nt = 0; nt < 8; ++nt)
#pragma unroll
                for (int mt = 0; mt < 4; ++mt)
                    acc[mt][nt] = __builtin_amdgcn_mfma_f32_16x16x32_bf16(af[mt], bc[2 * nt + kwc], acc[mt][nt], 0, 0, 0);
        }
    }

    // epilogue: bias+relu -> LDS transpose cs[120 w][264 (256 oc + pad)] -> coalesced store
    float cbv[4][4];
#pragma unroll
    for (int mt = 0; mt < 4; ++mt)
#pragma unroll
        for (int r = 0; r < 4; ++r)
            cbv[mt][r] = cb[wm + mt * 16 + (lane >> 4) * 4 + r];
    __syncthreads();
    ushort_t* cs = smem;                      // [120][264] (stride 528B = 132 words == 4 mod 32 -> 2-way)
#pragma unroll
    for (int nt = 0; nt < 8; ++nt) {
        int wg = nt * 16 + l16;
        if (wg < 120) {
#pragma unroll
            for (int mt = 0; mt < 4; ++mt)
#pragma unroll
                for (int r = 0; r < 4; ++r) {
                    int oc = wm + mt * 16 + (lane >> 4) * 4 + r;
                    float v = acc[mt][nt][r] + cbv[mt][r];
                    v = v > 0.f ? v : 0.f;
                    cs[wg * 264 + oc] = f2bf(v);
                }
        }
    }
    __syncthreads();
    ushort_t* Xbase = X + ((size_t)b * 90 + h) * 120 * 256;
    for (int idx = tid; idx < 3840; idx += 256) {            // 120*256/8 chunks
        int w = idx >> 5, c = (idx & 31) * 8;
        *(uint4*)&Xbase[(size_t)w * 256 + c] = *(const uint4*)&cs[w * 264 + c];
    }
}

// ---------------- K2: prim conv GEMM, split-K over patch positions ----------------
// grid (2, 4, 32) = (oc2 half, split, b); 256 thr; wave owns 32 rows x 112 cols
// P[s][oc2][b][n(112)] fp32 partials
__global__ __launch_bounds__(256) void k2_prim(const ushort_t* __restrict__ X,
                                               const ushort_t* __restrict__ A2,
                                               float* __restrict__ P) {
    const int tid = threadIdx.x, lane = tid & 63, wid = tid >> 6;
    const int mi = blockIdx.x, s = blockIdx.y, b = blockIdx.z;
    const int msub = mi * 128 + wid * 32;
    const int l16 = lane & 15, g8 = (lane >> 4) * 8;
    f32x4 acc[2][7] = {};
    size_t aoff[2];
#pragma unroll
    for (int t = 0; t < 2; ++t) aoff[t] = (size_t)(msub + t * 16 + l16) * 25600 + g8;
    size_t noff[7];
#pragma unroll
    for (int nt = 0; nt < 7; ++nt) {
        int n = nt * 16 + l16; n = n < 108 ? n : 107;   // pad cols clamp
        int h2 = n / 12, w2 = n % 12;
        noff[nt] = (((size_t)b * 90 + 10 * h2) * 120 + 10 * w2) * 256 + g8;
    }
#pragma unroll 1
    for (int p = s * 25; p < s * 25 + 25; ++p) {
        int ph = p / 10, pw = p % 10;
        size_t xb = (size_t)(ph * 120 + pw) * 256;
        size_t ab = (size_t)p * 256;
#pragma unroll
        for (int icc = 0; icc < 8; ++icc) {
            bf16x8 af[2], bfr[7];
#pragma unroll
            for (int t = 0; t < 2; ++t)
                af[t] = *(const bf16x8*)&A2[aoff[t] + ab + icc * 32];
#pragma unroll
            for (int nt = 0; nt < 7; ++nt)
                bfr[nt] = *(const bf16x8*)&X[noff[nt] + xb + icc * 32];
#pragma unroll
            for (int t = 0; t < 2; ++t)
#pragma unroll
                for (int nt = 0; nt < 7; ++nt)
                    acc[t][nt] = __builtin_amdgcn_mfma_f32_16x16x32_bf16(af[t], bfr[nt], acc[t][nt], 0, 0, 0);
        }
    }
#pragma unroll
    for (int t = 0; t < 2; ++t)
#pragma unroll
        for (int nt = 0; nt < 7; ++nt)
#pragma unroll
            for (int r = 0; r < 4; ++r) {
                int n   = nt * 16 + l16;
                int oc2 = msub + t * 16 + (lane >> 4) * 4 + r;
                P[(((size_t)s * 256 + oc2) * 32 + b) * 112 + n] = acc[t][nt][r];
            }
}

// ---------------- K3: reduce partials + prim bias + squash + caps prediction ----------------
// thread per (b,i); UP[b][i][80] fp32
__global__ __launch_bounds__(256) void k3_caps(const float* __restrict__ P,
                                               const float* __restrict__ prim_b,
                                               const float* __restrict__ caps_w,
                                               float* __restrict__ UP) {
    int t = blockIdx.x * 256 + threadIdx.x;   // grid 432*256 == 110,592 exactly
    int b = t / 3456, i = t % 3456;
    int cap = i / 108, hw = i % 108;
    float ud[8], l2 = 0.f;
#pragma unroll
    for (int d = 0; d < 8; ++d) {
        int oc2 = cap * 8 + d;
        float v = prim_b[oc2];
#pragma unroll
        for (int s = 0; s < 4; ++s)
            v += P[(((size_t)s * 256 + oc2) * 32 + b) * 112 + hw];
        ud[d] = v; l2 += v * v;
    }
    float scale = sqrtf(l2) / (1.f + l2);     // squash factor
#pragma unroll
    for (int d = 0; d < 8; ++d) ud[d] *= scale;
    const float* cw = caps_w + (size_t)i * 640;
    float* up = UP + ((size_t)b * 3456 + i) * 80;
    for (int j = 0; j < 80; j += 4) {
        f32x4 o = {0.f, 0.f, 0.f, 0.f};
#pragma unroll
        for (int d = 0; d < 8; ++d) {
            f32x4 w = *(const f32x4*)&cw[d * 80 + j];
            o += ud[d] * w;
        }
        *(f32x4*)&up[j] = o;
    }
}

// ---------------- K4: routing (3 iters) + logits + log_softmax ----------------
// one wg per batch; b_batch thread-private in registers
__global__ __launch_bounds__(256) void k4_route(const float* __restrict__ UP,
                                                const float* __restrict__ b_route,
                                                const float* __restrict__ pred_w,
                                                const float* __restrict__ pred_b,
                                                const float* __restrict__ eos_w,
                                                const float* __restrict__ eos_b,
                                                float* __restrict__ out) {
    __shared__ float sred[4][80];
    __shared__ __attribute__((aligned(16))) float sv[80];
    __shared__ float sscale[5];
    __shared__ float lg[130];
    __shared__ float lse[5];
    const int tid = threadIdx.x, lane = tid & 63, wid = tid >> 6;
    const int b = blockIdx.x;

    float br[14][5];
#pragma unroll
    for (int q = 0; q < 14; ++q) {
        int i = tid + q * 256;
        if (i < 3456)
#pragma unroll
            for (int o = 0; o < 5; ++o) br[q][o] = b_route[i * 5 + o];
    }

#pragma unroll 1
    for (int it = 0; it <= 3; ++it) {         // it 0: initial c/s/v; 1..3: routing iters
        f32x4 a4[20];
#pragma unroll
        for (int q = 0; q < 20; ++q) a4[q] = f32x4{0.f, 0.f, 0.f, 0.f};
#pragma unroll 1
        for (int q = 0; q < 14; ++q) {
            int i = tid + q * 256;
            if (i < 3456) {
                const float* up = UP + ((size_t)b * 3456 + i) * 80;
                f32x4 u4[20];
#pragma unroll
                for (int r = 0; r < 20; ++r) u4[r] = *(const f32x4*)&up[r * 4];
                float bo[5];
#pragma unroll
                for (int o = 0; o < 5; ++o) {
                    float bv = br[q][o];
                    if (it > 0) {
                        f32x4 dv = u4[o * 4 + 0] * (*(const f32x4*)&sv[o * 16 + 0])
                                 + u4[o * 4 + 1] * (*(const f32x4*)&sv[o * 16 + 4])
                                 + u4[o * 4 + 2] * (*(const f32x4*)&sv[o * 16 + 8])
                                 + u4[o * 4 + 3] * (*(const f32x4*)&sv[o * 16 + 12]);
                        bv += dv[0] + dv[1] + dv[2] + dv[3];
                        br[q][o] = bv;
                    }
                    bo[o] = bv;
                }
                float m = fmaxf(fmaxf(fmaxf(bo[0], bo[1]), fmaxf(bo[2], bo[3])), bo[4]);
                float e[5], sum = 0.f;
#pragma unroll
                for (int o = 0; o < 5; ++o) { e[o] = __expf(bo[o] - m); sum += e[o]; }
                float inv = 1.f / sum;
#pragma unroll
                for (int o = 0; o < 5; ++o) {
                    float c = e[o] * inv;
#pragma unroll
                    for (int q2 = 0; q2 < 4; ++q2) a4[o * 4 + q2] += c * u4[o * 4 + q2];
                }
            }
        }
        // reduce s across wave, then across waves
#pragma unroll
        for (int off = 32; off >= 1; off >>= 1)
#pragma unroll
            for (int q = 0; q < 20; ++q)
#pragma unroll
                for (int c = 0; c < 4; ++c) a4[q][c] += __shfl_xor(a4[q][c], off, 64);
        if (lane == 0)
#pragma unroll
            for (int q = 0; q < 20; ++q)
#pragma unroll
                for (int c = 0; c < 4; ++c) sred[wid][q * 4 + c] = a4[q][c];
        __syncthreads();
        if (tid < 80) sv[tid] = sred[0][tid] + sred[1][tid] + sred[2][tid] + sred[3][tid];
        __syncthreads();
        if (tid < 5) {
            float l2 = 0.f;
            for (int d = 0; d < 16; ++d) { float x = sv[tid * 16 + d]; l2 += x * x; }
            sscale[tid] = sqrtf(l2) / (1.f + l2);
        }
        __syncthreads();
        if (tid < 80) sv[tid] *= sscale[tid / 16];
        __syncthreads();                       // sv now holds v for next iter
    }
    // logits + log_softmax
    if (tid < 130) {
        int o = tid / 26, j = tid % 26;
        const float* wv = (j < 25) ? &pred_w[j * 16] : &eos_w[0];
        float dot = (j < 25) ? pred_b[j] : eos_b[0];
        for (int d = 0; d < 16; ++d) dot += sv[o * 16 + d] * wv[d];
        lg[tid] = dot;
    }
    __syncthreads();
    if (tid < 5) {
        float m = lg[tid * 26];
        for (int j = 1; j < 26; ++j) m = fmaxf(m, lg[tid * 26 + j]);
        float sum = 0.f;
        for (int j = 0; j < 26; ++j) sum += expf(lg[tid * 26 + j] - m);
        lse[tid] = m + logf(sum);
    }
    __syncthreads();
    if (tid < 130) out[b * 130 + tid] = lg[tid] - lse[tid / 26];
}

// ---------------- launch ----------------
extern "C" void kernel_launch(void* const* d_in, const int* in_sizes, int n_in,
                              void* d_out, int out_size, void* d_ws, size_t ws_size,
                              hipStream_t stream) {
    const float* inp    = (const float*)d_in[0];
    const float* w1     = (const float*)d_in[1];
    const float* cb1    = (const float*)d_in[2];
    const float* w2     = (const float*)d_in[3];
    const float* pb2    = (const float*)d_in[4];
    const float* capsw  = (const float*)d_in[5];
    const float* broute = (const float*)d_in[6];
    const float* predw  = (const float*)d_in[7];
    const float* predb  = (const float*)d_in[8];
    const float* eosw   = (const float*)d_in[9];
    const float* eosb   = (const float*)d_in[10];
    float* out = (float*)d_out;
    char* ws = (char*)d_ws;
    if (ws_size < WS_NEED) return;

    ushort_t* w1f = (ushort_t*)(ws + OFF_W1F);
    ushort_t* a2  = (ushort_t*)(ws + OFF_A2);
    ushort_t* X   = (ushort_t*)(ws + OFF_X);
    float*    P   = (float*)(ws + OFF_P);
    float*    UP  = (float*)(ws + OFF_UP);

    k0_w1   <<<dim3(600),      dim3(256), 0, stream>>>(w1, w1f);
    k0_a2   <<<dim3(256),      dim3(256), 0, stream>>>(w2, a2);
    k1_conv1<<<dim3(90, 32),   dim3(256), 0, stream>>>(inp, w1f, cb1, X);
    k2_prim <<<dim3(2, 4, 32), dim3(256), 0, stream>>>(X, a2, P);
    k3_caps <<<dim3(432),      dim3(256), 0, stream>>>(P, pb2, capsw, UP);
    k4_route<<<dim3(32),       dim3(256), 0, stream>>>(UP, broute, predw, predb, eosw, eosb, out);
}